// Round 7
// baseline (435.334 us; speedup 1.0000x reference)
//
#include <hip/hip_runtime.h>
#include <math.h>

typedef unsigned short u16;
typedef unsigned int u32;
typedef __bf16 bfv8 __attribute__((ext_vector_type(8)));
typedef float f32x4 __attribute__((ext_vector_type(4)));

#define BB 128
#define NN 197
#define DD 384
#define HH 1536
#define BN (BB*NN)   // 25216 = 197*128, multiple of 128
#define NP 224       // padded attention dim (multiple of 32)

__device__ __forceinline__ u16 f2bf(float x){ u32 u; __builtin_memcpy(&u,&x,4); u = (u + 0x7fffu + ((u>>16)&1u))>>16; return (u16)u; }

__device__ __forceinline__ float fast_gelu(float z){
  // 0.5*z*(1+tanh(t)) == z * sigmoid(2t), t = 0.7978845608*z*(1+0.044715*z^2)
  float t2 = 1.5957691216f*z*(1.f + 0.044715f*z*z);
  return z * __builtin_amdgcn_rcpf(1.f + __expf(-t2));
}

__device__ __forceinline__ void gload16(const void* g, void* s){
  __builtin_amdgcn_global_load_lds(
      (const __attribute__((address_space(1))) void*)g,
      (__attribute__((address_space(3))) void*)s, 16, 0, 0);
}

// ---------------- LN1 row stats ----------------
__global__ __launch_bounds__(256) void ln1_stats(const float* __restrict__ x,
    float* __restrict__ mu, float* __restrict__ rv){
  int row = blockIdx.x*4 + (threadIdx.x>>6);
  int lane = threadIdx.x & 63;
  const float* xr = x + (long)row*DD;
  float s=0.f, ss=0.f;
  #pragma unroll
  for (int j=0;j<DD/64;j++){ float v = xr[lane + j*64]; s+=v; ss+=v*v; }
  #pragma unroll
  for (int m=32;m;m>>=1){ s += __shfl_xor(s,m); ss += __shfl_xor(ss,m); }
  if (lane==0){
    float mn = s*(1.f/DD);
    float var = ss*(1.f/DD) - mn*mn;
    mu[row]=mn; rv[row]=1.f/sqrtf(var+1e-5f);
  }
}

// ---------------- patch-axis norm scale: scale[b,d] ----------------
__global__ __launch_bounds__(256) void colnorm(const float* __restrict__ x,
    const float* __restrict__ mu, const float* __restrict__ rv,
    const float* __restrict__ g, const float* __restrict__ bt,
    float* __restrict__ scale){
  int i = blockIdx.x*256 + threadIdx.x;  // b*DD + d, exact grid
  int b = i/DD, d = i - b*DD;
  const float* xp = x + (long)b*NN*DD + d;
  float gd = g[d], bd = bt[d];
  float s = 0.f;
  for (int n=0;n<NN;n++){
    float v = (xp[(long)n*DD] - mu[b*NN+n]) * rv[b*NN+n] * gd + bd;
    s += v*v;
  }
  scale[i] = 1.f/sqrtf(s + 197.f*1e-4f + 1e-8f);
}

// ---------------- apply LN1 + patch scale -> bf16 ----------------
__global__ __launch_bounds__(256) void ln_apply(const float* __restrict__ x,
    const float* __restrict__ mu, const float* __restrict__ rv,
    const float* __restrict__ g, const float* __restrict__ bt,
    const float* __restrict__ scale, u16* __restrict__ inpn){
  long i = (long)blockIdx.x*256 + threadIdx.x;  // exact grid: BN*DD
  int d = (int)(i % DD);
  long row = i / DD;
  int b = (int)(row / NN);
  float v = (x[i]-mu[row])*rv[row]*g[d]+bt[d];
  inpn[i] = f2bf(v * scale[b*DD+d]);
}

// ---------------- weight cast/transpose ----------------
__global__ __launch_bounds__(256) void prep_weights(const float* __restrict__ V, const float* __restrict__ W,
    const float* __restrict__ W1, const float* __restrict__ W2,
    u16* __restrict__ Vb, u16* __restrict__ Wt, u16* __restrict__ W1t, u16* __restrict__ W2t){
  int i = blockIdx.x*256 + threadIdx.x;   // exact grid: DD*HH = 589824
  if (i < DD*DD){
    Vb[i] = f2bf(V[i]);                   // V used as-is: U = inpn . V^T (NT)
    int r = i/DD, c = i - r*DD;
    Wt[c*DD + r] = f2bf(W[i]);            // W^T
  }
  {
    int r = i/HH, c = i - r*HH;           // W1 [DD][HH]
    W1t[(long)c*DD + r] = f2bf(W1[i]);    // W1^T [HH][DD]
    int r2 = i/DD, c2 = i - r2*DD;        // W2 [HH][DD]
    W2t[(long)c2*HH + r2] = f2bf(W2[i]);  // W2^T [DD][HH]
  }
}

// ---------------- row softmax over 197, write bf16 padded to 224 ----------------
__global__ __launch_bounds__(256) void softmax_rows(const float* __restrict__ S, u16* __restrict__ attn){
  int row = blockIdx.x*4 + (threadIdx.x>>6);
  int lane = threadIdx.x & 63;
  const float* sr = S + (long)row*NP;
  float v[4]; float mx = -1e30f;
  #pragma unroll
  for (int j=0;j<4;j++){ int c = lane + j*64; v[j] = (c<NN)? sr[c] : -1e30f; mx = fmaxf(mx, v[j]); }
  #pragma unroll
  for (int m=32;m;m>>=1) mx = fmaxf(mx, __shfl_xor(mx,m));
  float sm = 0.f;
  #pragma unroll
  for (int j=0;j<4;j++){ v[j] = __expf(v[j]-mx); sm += v[j]; }   // pads -> 0
  #pragma unroll
  for (int m=32;m;m>>=1) sm += __shfl_xor(sm,m);
  float inv = __builtin_amdgcn_rcpf(sm);
  u16* ar = attn + (long)row*NP;
  #pragma unroll
  for (int j=0;j<4;j++){ int c = lane + j*64; if (c<NP) ar[c] = f2bf(v[j]*inv); }
}

// ---------------- LN2 fused (stats + apply) -> bf16 ----------------
__global__ __launch_bounds__(256) void ln2_fused(const float* __restrict__ x2,
    const float* __restrict__ g, const float* __restrict__ bt, u16* __restrict__ h){
  int row = blockIdx.x*4 + (threadIdx.x>>6);
  int lane = threadIdx.x & 63;
  const float* xr = x2 + (long)row*DD;
  float v[6]; float s=0.f, ss=0.f;
  #pragma unroll
  for (int j=0;j<6;j++){ v[j]=xr[lane+j*64]; s+=v[j]; ss+=v[j]*v[j]; }
  #pragma unroll
  for (int m=32;m;m>>=1){ s+=__shfl_xor(s,m); ss+=__shfl_xor(ss,m); }
  float mn = s*(1.f/DD);
  float rvv = 1.f/sqrtf(ss*(1.f/DD)-mn*mn+1e-5f);
  u16* hr = h + (long)row*DD;
  #pragma unroll
  for (int j=0;j<6;j++){ int d = lane+j*64; hr[d] = f2bf((v[j]-mn)*rvv*g[d]+bt[d]); }
}

// ---------------- epilogue functors ----------------
// Each gets mf 16-row fragments x 1 col: rows r0 + m*16 + i, column c, value col[m][i]
struct EpiUt { u16* ut;                      // write sqrt(acc^2+1e-8) transposed: Ut[b][d][n]
  __device__ void operator()(int, int r0, int c, const f32x4* col, int mf) const {
    for (int m=0;m<mf;m++)
      #pragma unroll
      for (int i=0;i<4;i++){
        int r = r0 + m*16 + i;
        int b = r/NN, p = r - b*NN;
        float v = col[m][i];
        ut[((long)b*DD + c)*NP + p] = f2bf(sqrtf(v*v + 1e-8f));
      }
  }};
struct EpiY { u16* y;
  __device__ void operator()(int, int r0, int c, const f32x4* col, int mf) const {
    u16* yp = y + (long)r0*DD + c;
    for (int m=0;m<mf;m++)
      #pragma unroll
      for (int i=0;i<4;i++)
        yp[(long)(m*16+i)*DD] = f2bf(col[m][i]);
  }};
struct EpiS { float* s;
  __device__ void operator()(int b, int r0, int c, const f32x4* col, int mf) const {
    float* sp = s + ((long)b*NN + r0)*NP + c;
    for (int m=0;m<mf;m++)
      #pragma unroll
      for (int i=0;i<4;i++){
        int r = r0 + m*16 + i;
        float v = col[m][i];
        if (r < NN) sp[(long)(m*16+i)*NP] = sqrtf(v*v + 1e-8f);
      }
  }};
struct EpiX2 { float* x2; const float* x;
  __device__ void operator()(int b, int r0, int c, const f32x4* col, int mf) const {
    long base = ((long)b*NN + r0)*DD + c;
    for (int m=0;m<mf;m++)
      #pragma unroll
      for (int i=0;i<4;i++){
        int r = r0 + m*16 + i;
        if (r < NN){ long idx = base + (long)(m*16+i)*DD; x2[idx] = x[idx] + col[m][i]; }
      }
  }};
struct EpiGelu { u16* g; const float* b1;
  __device__ void operator()(int, int r0, int c, const f32x4* col, int mf) const {
    float bb = b1[c];
    u16* gp = g + (long)r0*HH + c;
    for (int m=0;m<mf;m++)
      #pragma unroll
      for (int i=0;i<4;i++)
        gp[(long)(m*16+i)*HH] = f2bf(fast_gelu(col[m][i] + bb));
  }};
struct EpiOut { float* o; const float* x2; const float* b2;
  __device__ void operator()(int, int r0, int c, const f32x4* col, int mf) const {
    float bb = b2[c];
    long base = (long)r0*DD + c;
    for (int m=0;m<mf;m++)
      #pragma unroll
      for (int i=0;i<4;i++){
        long idx = base + (long)(m*16+i)*DD;
        o[idx] = x2[idx] + col[m][i] + bb;
      }
  }};

// ---------------- generic NT GEMM: C = A(MxK) * B(NxK)^T, bf16 in, fp32 acc ----------------
// BM x 128 tile, BK=32, 4 waves (2x2), wave tile (BM/2)x64, MFMA 16x16x32.
// D-deep counted-vmcnt pipeline (T4/m218): D LDS buffers, (D-1) tiles in flight,
// steady-state wait vmcnt((D-2)*L) -- never drained to 0 until the tail.
// K-slot XOR swizzle (rule 21): linear global_load_lds dest + inverse-swizzled
// GLOBAL source + swizzled ds_read. Breaks the 8-way bank conflict of [row][32]
// bf16 tiles (rows 64B apart -> row*16 mod 32 takes 2 values).
// XCD-aware bijective blockIdx swizzle (T1/m204) for A-panel L2 sharing.
#define WAITV(N) asm volatile("s_waitcnt vmcnt(" #N ")" ::: "memory")
template<int BM, int D, class Epi>
__global__ __launch_bounds__(256) void gemm_nt(const u16* __restrict__ A, const u16* __restrict__ B,
    int M, int N, int K, int lda, int ldb, long sA, long sB, int NT, Epi epi)
{
  constexpr int MF = BM/32;          // row fragments per wave
  constexpr int ALOADS = BM/64;      // gload16 per thread for A tile
  constexpr int L = ALOADS + 2;      // loads per stage per thread
  __shared__ __align__(16) u16 As[D][BM*32];
  __shared__ __align__(16) u16 Bs[D][128*32];
  int wg;
  { int flat = blockIdx.x, nwg = gridDim.x;
    int xcd = flat & 7, local = flat >> 3;
    int q = nwg >> 3, r = nwg & 7;
    wg = (xcd < r ? xcd*(q+1) : r*(q+1) + (xcd-r)*q) + local; }
  const int bm = wg / NT, bn = wg - bm*NT;
  const int bat = blockIdx.y;
  const u16* Ab = A + (long)bat*sA;
  const u16* Bb = B + (long)bat*sB;
  const int t = threadIdx.x, lane = t&63, wid = t>>6, wr = wid>>1, wc = wid&1;
  const int row0 = bm*BM, col0 = bn*128;

  // staging offsets: LDS dest linear (ob); global source k-slot inverse-swizzled
  long aoff[ALOADS]; int asoff[ALOADS];
  #pragma unroll
  for (int i=0;i<ALOADS;i++){
    int ob = (i*256+t)*16;
    int r = ob>>6;                       // tile row (64B per row of 32 bf16)
    int sg = ((ob>>4)&3) ^ (r&3) ^ ((r>>2)&3);   // swizzled k-slot (8 bf16 each)
    int ra = row0+r; if (ra>M-1) ra=M-1; // clamp edge rows (valid mem, outputs guarded)
    aoff[i] = (long)ra*lda + sg*8; asoff[i] = ob;
  }
  long boff[2]; int bsoff[2];
  #pragma unroll
  for (int i=0;i<2;i++){
    int ob = (i*256+t)*16;
    int r = ob>>6;
    int sg = ((ob>>4)&3) ^ (r&3) ^ ((r>>2)&3);
    int rb = col0+r; if (rb>N-1) rb=N-1;
    boff[i] = (long)rb*ldb + sg*8; bsoff[i] = ob;
  }

  auto stage = [&](int buf, int k0){
    #pragma unroll
    for (int i=0;i<ALOADS;i++) gload16(Ab + aoff[i] + k0, (char*)As[buf] + asoff[i]);
    #pragma unroll
    for (int i=0;i<2;i++)      gload16(Bb + boff[i] + k0, (char*)Bs[buf] + bsoff[i]);
  };

  f32x4 acc[MF][4] = {};
  const int rl = lane&15, kslot = lane>>4;
  const int ntile = K/32;

  #pragma unroll
  for (int p=0;p<D-1;p++) if (p < ntile) stage(p, p*32);

  for (int tt=0; tt<ntile; ++tt){
    const int buf = tt % D;
    {
      int rem = ntile - 1 - tt;                 // stages beyond current
      int nf = rem < D-2 ? rem : D-2;           // stages left in flight after wait
      if constexpr (L==3){
        if (nf>=2) WAITV(6); else if (nf==1) WAITV(3); else WAITV(0);
      } else {
        if (nf>=2) WAITV(8); else if (nf==1) WAITV(4); else WAITV(0);
      }
    }
    __builtin_amdgcn_sched_barrier(0);
    __builtin_amdgcn_s_barrier();      // all waves' portions of tile tt landed

    bfv8 af[MF], bfr[4];
    #pragma unroll
    for (int m=0;m<MF;m++){
      int rowA = wr*(BM/2) + m*16 + rl;
      int sl = kslot ^ (rowA&3) ^ ((rowA>>2)&3);
      af[m] = *(const bfv8*)((const char*)As[buf] + rowA*64 + sl*16);
    }
    #pragma unroll
    for (int n=0;n<4;n++){
      int rowB = wc*64 + n*16 + rl;
      int sl = kslot ^ (rowB&3) ^ ((rowB>>2)&3);
      bfr[n] = *(const bfv8*)((const char*)Bs[buf] + rowB*64 + sl*16);
    }
    #pragma unroll
    for (int m=0;m<MF;m++)
      #pragma unroll
      for (int n=0;n<4;n++)
        acc[m][n] = __builtin_amdgcn_mfma_f32_16x16x32_bf16(af[m], bfr[n], acc[m][n], 0,0,0);

    __builtin_amdgcn_s_barrier();      // all waves consumed buf
    __builtin_amdgcn_sched_barrier(0);
    if (tt+D-1 < ntile) stage((tt+D-1)%D, (tt+D-1)*32);   // refill freed buffer
  }

  const int rbase = row0 + wr*(BM/2) + (lane>>4)*4;
  const int cbase = col0 + wc*64 + rl;
  #pragma unroll
  for (int n=0;n<4;n++){
    int c = cbase + n*16;
    if (c < N){
      f32x4 colv[MF];
      #pragma unroll
      for (int m=0;m<MF;m++) colv[m] = acc[m][n];
      epi(bat, rbase, c, colv, MF);
    }
  }
}

extern "C" void kernel_launch(void* const* d_in, const int* in_sizes, int n_in,
                              void* d_out, int out_size, void* d_ws, size_t ws_size,
                              hipStream_t stream){
  const float* x     = (const float*)d_in[0];
  const float* g1    = (const float*)d_in[1];
  const float* b1n   = (const float*)d_in[2];
  const float* V     = (const float*)d_in[3];
  const float* W     = (const float*)d_in[4];
  const float* g2    = (const float*)d_in[5];
  const float* b2n   = (const float*)d_in[6];
  const float* W1    = (const float*)d_in[7];
  const float* bias1 = (const float*)d_in[8];
  const float* W2    = (const float*)d_in[9];
  const float* bias2 = (const float*)d_in[10];
  float* out = (float*)d_out;

  char* ws = (char*)d_ws;
  size_t off = 0;
  auto take = [&](size_t bytes)->char*{ char* p = ws + off; off += (bytes + 255) & ~(size_t)255; return p; };

  float* mu    = (float*)take((size_t)BN*4);
  float* rv    = (float*)take((size_t)BN*4);
  float* scale = (float*)take((size_t)BB*DD*4);
  char* aliasBase = ws + off;                       // gelu buffer aliases the next 4 (dead by then)
  u16*  inpn = (u16*) take((size_t)BN*DD*2);
  u16*  Ut   = (u16*) take((size_t)BB*DD*NP*2);
  u16*  Yb   = (u16*) take((size_t)BN*DD*2);
  float* S   = (float*)take((size_t)BN*NP*4);
  u16*  attn = (u16*) take((size_t)BN*NP*2);
  float* x2  = (float*)take((size_t)BN*DD*4);
  u16*  h    = (u16*) take((size_t)BN*DD*2);
  u16*  Vb   = (u16*) take((size_t)DD*DD*2);
  u16*  Wt   = (u16*) take((size_t)DD*DD*2);
  u16*  W1t  = (u16*) take((size_t)DD*HH*2);
  u16*  W2t  = (u16*) take((size_t)DD*HH*2);
  u16*  G    = (u16*)aliasBase;                     // 77.5MB <= 83.3MB region

  prep_weights<<<DD*HH/256, 256, 0, stream>>>(V, W, W1, W2, Vb, Wt, W1t, W2t);
  ln1_stats  <<<BN/4,       256, 0, stream>>>(x, mu, rv);
  colnorm    <<<BB*DD/256,  256, 0, stream>>>(x, mu, rv, g1, b1n, scale);
  ln_apply   <<<BN*DD/256,  256, 0, stream>>>(x, mu, rv, g1, b1n, scale, inpn);
  (void)hipMemsetAsync(Ut, 0, (size_t)BB*DD*NP*2, stream);   // zero K-pad for GEMM4

  // GEMM1: Ut[b,d,n] = |inpn . V^T|   (BM=64: 394*3 = 1182 blocks)
  { dim3 grid(394*3, 1);
    gemm_nt<64,4,EpiUt><<<grid,256,0,stream>>>(inpn, Vb, BN, DD, DD, DD, DD, 0, 0, 3, EpiUt{Ut}); }
  // GEMM2: Y = inpn . W
  { dim3 grid(394*3, 1);
    gemm_nt<64,4,EpiY><<<grid,256,0,stream>>>(inpn, Wt, BN, DD, DD, DD, DD, 0, 0, 3, EpiY{Yb}); }
  // GEMM3 (batched): S = |Y . inpn^T|   (M-tiles ceil(197/64)=4, NT=2)
  { dim3 grid(4*2, BB);
    gemm_nt<64,4,EpiS><<<grid,256,0,stream>>>(Yb, inpn, NN, NN, DD, DD, DD,
                                         (long)NN*DD, (long)NN*DD, 2, EpiS{S}); }
  softmax_rows<<<BN/4, 256, 0, stream>>>(S, attn);
  // GEMM4 (batched): x2 = x + attn . Ut^T   (K=224 zero-padded both sides, ntile=7)
  { dim3 grid(4*3, BB);
    gemm_nt<64,4,EpiX2><<<grid,256,0,stream>>>(attn, Ut, NN, DD, NP, NP, NP,
                                          (long)NN*NP, (long)DD*NP, 3, EpiX2{x2, x}); }
  ln2_fused<<<BN/4, 256, 0, stream>>>(x2, g2, b2n, h);
  // GEMM5: G = gelu(h . W1 + b1)   (BM=128: 197*12 = 2364 blocks, D=3)
  { dim3 grid(197*12, 1);
    gemm_nt<128,3,EpiGelu><<<grid,256,0,stream>>>(h, W1t, BN, HH, DD, DD, DD, 0, 0, 12, EpiGelu{G, bias1}); }
  // GEMM6: out = x2 + G . W2 + b2   (BM=64: 394*3 = 1182 blocks, D=4)
  { dim3 grid(394*3, 1);
    gemm_nt<64,4,EpiOut><<<grid,256,0,stream>>>(G, W2t, BN, DD, HH, HH, HH, 0, 0, 3, EpiOut{out, x2, bias2}); }
}

// Round 8
// 395.075 us; speedup vs baseline: 1.1019x; 1.1019x over previous
//
#include <hip/hip_runtime.h>
#include <math.h>

typedef unsigned short u16;
typedef unsigned int u32;
typedef __bf16 bfv8 __attribute__((ext_vector_type(8)));
typedef float f32x4 __attribute__((ext_vector_type(4)));

#define BB 128
#define NN 197
#define DD 384
#define HH 1536
#define BN (BB*NN)   // 25216 = 197*128, multiple of 128
#define NP 224       // padded attention dim (multiple of 32)

__device__ __forceinline__ float bf2f(u16 h){ u32 u = ((u32)h)<<16; float f; __builtin_memcpy(&f,&u,4); return f; }
__device__ __forceinline__ u16 f2bf(float x){ u32 u; __builtin_memcpy(&u,&x,4); u = (u + 0x7fffu + ((u>>16)&1u))>>16; return (u16)u; }

__device__ __forceinline__ float fast_gelu(float z){
  float t2 = 1.5957691216f*z*(1.f + 0.044715f*z*z);
  return z * __builtin_amdgcn_rcpf(1.f + __expf(-t2));
}

__device__ __forceinline__ void gload16(const void* g, void* s){
  __builtin_amdgcn_global_load_lds(
      (const __attribute__((address_space(1))) void*)g,
      (__attribute__((address_space(3))) void*)s, 16, 0, 0);
}

#define WAITV(N) asm volatile("s_waitcnt vmcnt(" #N ")" ::: "memory")

// ---------------- LN1 row stats ----------------
__global__ __launch_bounds__(256) void ln1_stats(const float* __restrict__ x,
    float* __restrict__ mu, float* __restrict__ rv){
  int row = blockIdx.x*4 + (threadIdx.x>>6);
  int lane = threadIdx.x & 63;
  const float* xr = x + (long)row*DD;
  float s=0.f, ss=0.f;
  #pragma unroll
  for (int j=0;j<DD/64;j++){ float v = xr[lane + j*64]; s+=v; ss+=v*v; }
  #pragma unroll
  for (int m=32;m;m>>=1){ s += __shfl_xor(s,m); ss += __shfl_xor(ss,m); }
  if (lane==0){
    float mn = s*(1.f/DD);
    float var = ss*(1.f/DD) - mn*mn;
    mu[row]=mn; rv[row]=1.f/sqrtf(var+1e-5f);
  }
}

// ---------------- patch-axis norm scale: scale[b,d] ----------------
__global__ __launch_bounds__(256) void colnorm(const float* __restrict__ x,
    const float* __restrict__ mu, const float* __restrict__ rv,
    const float* __restrict__ g, const float* __restrict__ bt,
    float* __restrict__ scale){
  int i = blockIdx.x*256 + threadIdx.x;  // b*DD + d, exact grid
  int b = i/DD, d = i - b*DD;
  const float* xp = x + (long)b*NN*DD + d;
  float gd = g[d], bd = bt[d];
  float s = 0.f;
  for (int n=0;n<NN;n++){
    float v = (xp[(long)n*DD] - mu[b*NN+n]) * rv[b*NN+n] * gd + bd;
    s += v*v;
  }
  scale[i] = 1.f/sqrtf(s + 197.f*1e-4f + 1e-8f);
}

// ---------------- apply LN1 + patch scale -> bf16 ----------------
__global__ __launch_bounds__(256) void ln_apply(const float* __restrict__ x,
    const float* __restrict__ mu, const float* __restrict__ rv,
    const float* __restrict__ g, const float* __restrict__ bt,
    const float* __restrict__ scale, u16* __restrict__ inpn){
  long i = (long)blockIdx.x*256 + threadIdx.x;  // exact grid: BN*DD
  int d = (int)(i % DD);
  long row = i / DD;
  int b = (int)(row / NN);
  float v = (x[i]-mu[row])*rv[row]*g[d]+bt[d];
  inpn[i] = f2bf(v * scale[b*DD+d]);
}

// ---------------- weight cast/transpose ----------------
__global__ __launch_bounds__(256) void prep_weights(const float* __restrict__ V, const float* __restrict__ W,
    const float* __restrict__ W1, const float* __restrict__ W2,
    u16* __restrict__ Vb, u16* __restrict__ Wt, u16* __restrict__ W1t, u16* __restrict__ W2t){
  int i = blockIdx.x*256 + threadIdx.x;   // exact grid: DD*HH = 589824
  if (i < DD*DD){
    Vb[i] = f2bf(V[i]);                   // V used as-is: U = inpn . V^T (NT)
    int r = i/DD, c = i - r*DD;
    Wt[c*DD + r] = f2bf(W[i]);            // W^T
  }
  {
    int r = i/HH, c = i - r*HH;           // W1 [DD][HH]
    W1t[(long)c*DD + r] = f2bf(W1[i]);    // W1^T [HH][DD]
    int r2 = i/DD, c2 = i - r2*DD;        // W2 [HH][DD]
    W2t[(long)c2*HH + r2] = f2bf(W2[i]);  // W2^T [DD][HH]
  }
}

// ---------------- transpose + pad: U[b][n][d] -> Ut[b][d][n(224, zero-pad)] ----------------
__global__ __launch_bounds__(256) void transpose_pad(const u16* __restrict__ U, u16* __restrict__ Ut){
  __shared__ u16 tile[32][33];
  int b = blockIdx.x, dt = blockIdx.y, pt = blockIdx.z;
  int tx = threadIdx.x & 31, ty = threadIdx.x >> 5;   // 32 x 8
  const u16* Ub = U + (long)b*NN*DD;
  #pragma unroll
  for (int j=0;j<4;j++){
    int p = pt*32 + ty + j*8;
    int d = dt*32 + tx;
    tile[ty+j*8][tx] = (p<NN) ? Ub[(long)p*DD + d] : (u16)0;
  }
  __syncthreads();
  u16* Utb = Ut + (long)b*DD*NP;
  #pragma unroll
  for (int j=0;j<4;j++){
    int d = dt*32 + ty + j*8;
    int p = pt*32 + tx;
    Utb[(long)d*NP + p] = tile[tx][ty+j*8];
  }
}

// ---------------- row softmax over 197 (bf16 in), write bf16 padded to 224 ----------------
__global__ __launch_bounds__(256) void softmax_rows(const u16* __restrict__ S, u16* __restrict__ attn){
  int row = blockIdx.x*4 + (threadIdx.x>>6);
  int lane = threadIdx.x & 63;
  const u16* sr = S + (long)row*NP;
  float v[4]; float mx = -1e30f;
  #pragma unroll
  for (int j=0;j<4;j++){ int c = lane + j*64; v[j] = (c<NN)? bf2f(sr[c]) : -1e30f; mx = fmaxf(mx, v[j]); }
  #pragma unroll
  for (int m=32;m;m>>=1) mx = fmaxf(mx, __shfl_xor(mx,m));
  float sm = 0.f;
  #pragma unroll
  for (int j=0;j<4;j++){ v[j] = __expf(v[j]-mx); sm += v[j]; }   // pads -> 0
  #pragma unroll
  for (int m=32;m;m>>=1) sm += __shfl_xor(sm,m);
  float inv = __builtin_amdgcn_rcpf(sm);
  u16* ar = attn + (long)row*NP;
  #pragma unroll
  for (int j=0;j<4;j++){ int c = lane + j*64; if (c<NP) ar[c] = f2bf(v[j]*inv); }
}

// ---------------- LN2 fused (stats + apply), bf16 x2 in -> bf16 h ----------------
__global__ __launch_bounds__(256) void ln2_fused(const u16* __restrict__ x2,
    const float* __restrict__ g, const float* __restrict__ bt, u16* __restrict__ h){
  int row = blockIdx.x*4 + (threadIdx.x>>6);
  int lane = threadIdx.x & 63;
  const u16* xr = x2 + (long)row*DD;
  float v[6]; float s=0.f, ss=0.f;
  #pragma unroll
  for (int j=0;j<6;j++){ v[j]=bf2f(xr[lane+j*64]); s+=v[j]; ss+=v[j]*v[j]; }
  #pragma unroll
  for (int m=32;m;m>>=1){ s+=__shfl_xor(s,m); ss+=__shfl_xor(ss,m); }
  float mn = s*(1.f/DD);
  float rvv = 1.f/sqrtf(ss*(1.f/DD)-mn*mn+1e-5f);
  u16* hr = h + (long)row*DD;
  #pragma unroll
  for (int j=0;j<6;j++){ int d = lane+j*64; hr[d] = f2bf((v[j]-mn)*rvv*g[d]+bt[d]); }
}

// ---------------- epilogue functors ----------------
struct EpiS { u16* s;                        // bf16 S
  __device__ void operator()(int b, int r0, int c, const f32x4* col, int mf) const {
    u16* sp = s + ((long)b*NN + r0)*NP + c;
    for (int m=0;m<mf;m++)
      #pragma unroll
      for (int i=0;i<4;i++){
        int r = r0 + m*16 + i;
        float v = col[m][i];
        if (r < NN) sp[(long)(m*16+i)*NP] = f2bf(sqrtf(v*v + 1e-8f));
      }
  }};
struct EpiX2 { u16* x2; const float* x;      // bf16 x2 = x + t
  __device__ void operator()(int b, int r0, int c, const f32x4* col, int mf) const {
    long base = ((long)b*NN + r0)*DD + c;
    for (int m=0;m<mf;m++)
      #pragma unroll
      for (int i=0;i<4;i++){
        int r = r0 + m*16 + i;
        if (r < NN){ long idx = base + (long)(m*16+i)*DD; x2[idx] = f2bf(x[idx] + col[m][i]); }
      }
  }};
struct EpiGelu { u16* g; const float* b1;
  __device__ void operator()(int, int r0, int c, const f32x4* col, int mf) const {
    float bb = b1[c];
    u16* gp = g + (long)r0*HH + c;
    for (int m=0;m<mf;m++)
      #pragma unroll
      for (int i=0;i<4;i++)
        gp[(long)(m*16+i)*HH] = f2bf(fast_gelu(col[m][i] + bb));
  }};
struct EpiOut { float* o; const u16* x2; const float* b2;
  __device__ void operator()(int, int r0, int c, const f32x4* col, int mf) const {
    float bb = b2[c];
    long base = (long)r0*DD + c;
    for (int m=0;m<mf;m++)
      #pragma unroll
      for (int i=0;i<4;i++){
        long idx = base + (long)(m*16+i)*DD;
        o[idx] = bf2f(x2[idx]) + col[m][i] + bb;
      }
  }};

// ---------------- generic NT GEMM (r6 schedule): C = A(MxK) * B(NxK)^T ----------------
// BM x 128 tile, BK=32, 4 waves (2x2), 2-buffer counted-vmcnt pipeline (T4):
//   wait vmcnt(L) -> s_barrier -> ds_read+MFMA -> s_barrier -> restage freed buf
// XCD-aware bijective blockIdx swizzle (T1/m204) for A-panel L2 sharing.
template<int BM, class Epi>
__global__ __launch_bounds__(256) void gemm_nt(const u16* __restrict__ A, const u16* __restrict__ B,
    int M, int N, int K, int lda, int ldb, long sA, long sB, int NT, Epi epi)
{
  constexpr int MF = BM/32;          // row fragments per wave
  constexpr int ALOADS = BM/64;      // gload16 per thread for A tile
  __shared__ __align__(16) u16 As[2][BM*32];
  __shared__ __align__(16) u16 Bs[2][128*32];
  int wg;
  { int flat = blockIdx.x, nwg = gridDim.x;
    int xcd = flat & 7, local = flat >> 3;
    int q = nwg >> 3, r = nwg & 7;
    wg = (xcd < r ? xcd*(q+1) : r*(q+1) + (xcd-r)*q) + local; }
  const int bm = wg / NT, bn = wg - bm*NT;
  const int bat = blockIdx.y;
  const u16* Ab = A + (long)bat*sA;
  const u16* Bb = B + (long)bat*sB;
  const int t = threadIdx.x, lane = t&63, wid = t>>6, wr = wid>>1, wc = wid&1;
  const int row0 = bm*BM, col0 = bn*128;

  long aoff[ALOADS]; int asoff[ALOADS];
  #pragma unroll
  for (int i=0;i<ALOADS;i++){
    int ob = (i*256+t)*16;
    int r = ob>>6, ke = (ob&63)>>1;
    int ra = row0+r; if (ra>M-1) ra=M-1;   // clamp edge rows (valid mem, outputs guarded)
    aoff[i] = (long)ra*lda + ke; asoff[i] = ob;
  }
  long boff[2]; int bsoff[2];
  #pragma unroll
  for (int i=0;i<2;i++){
    int ob = (i*256+t)*16;
    int r = ob>>6, ke = (ob&63)>>1;
    int rb = col0+r; if (rb>N-1) rb=N-1;
    boff[i] = (long)rb*ldb + ke; bsoff[i] = ob;
  }

  auto stage = [&](int buf, int k0){
    #pragma unroll
    for (int i=0;i<ALOADS;i++) gload16(Ab + aoff[i] + k0, (char*)As[buf] + asoff[i]);
    #pragma unroll
    for (int i=0;i<2;i++)      gload16(Bb + boff[i] + k0, (char*)Bs[buf] + bsoff[i]);
  };

  f32x4 acc[MF][4] = {};
  const int kg = (lane>>4)*8, rl = lane&15;
  const int ntile = K/32;

  stage(0, 0);
  stage(1, 32);
  int buf = 0;
  for (int tt=0; tt<ntile; ++tt){
    if (tt+1 < ntile){
      if constexpr (ALOADS == 1) WAITV(3); else WAITV(4);
    } else {
      WAITV(0);
    }
    __builtin_amdgcn_sched_barrier(0);
    __builtin_amdgcn_s_barrier();      // all waves' portions of tile tt landed

    bfv8 af[MF], bfr[4];
    #pragma unroll
    for (int m=0;m<MF;m++) af[m]  = *(const bfv8*)&As[buf][(wr*(BM/2) + m*16 + rl)*32 + kg];
    #pragma unroll
    for (int n=0;n<4;n++)  bfr[n] = *(const bfv8*)&Bs[buf][(wc*64 + n*16 + rl)*32 + kg];
    #pragma unroll
    for (int m=0;m<MF;m++)
      #pragma unroll
      for (int n=0;n<4;n++)
        acc[m][n] = __builtin_amdgcn_mfma_f32_16x16x32_bf16(af[m], bfr[n], acc[m][n], 0,0,0);

    __builtin_amdgcn_s_barrier();      // all waves consumed buf
    __builtin_amdgcn_sched_barrier(0);
    if (tt+2 < ntile) stage(buf, (tt+2)*32);
    buf ^= 1;
  }

  const int rbase = row0 + wr*(BM/2) + (lane>>4)*4;
  const int cbase = col0 + wc*64 + rl;
  #pragma unroll
  for (int n=0;n<4;n++){
    int c = cbase + n*16;
    if (c < N){
      f32x4 colv[MF];
      #pragma unroll
      for (int m=0;m<MF;m++) colv[m] = acc[m][n];
      epi(bat, rbase, c, colv, MF);
    }
  }
}

// ---------------- fused GEMM1+GEMM2: one A-stage, two Bs ----------------
// U = |inpn . V^T| (natural layout, coalesced), Y = inpn . W. M=BN, N=K=384, BM=64.
__global__ __launch_bounds__(256) void gemm12(const u16* __restrict__ A,
    const u16* __restrict__ B1, const u16* __restrict__ B2,
    u16* __restrict__ U, u16* __restrict__ Y)
{
  __shared__ __align__(16) u16 As[2][64*32];
  __shared__ __align__(16) u16 B1s[2][128*32];
  __shared__ __align__(16) u16 B2s[2][128*32];
  int wg;
  { int flat = blockIdx.x, nwg = gridDim.x;
    int xcd = flat & 7, local = flat >> 3;
    int q = nwg >> 3, r = nwg & 7;
    wg = (xcd < r ? xcd*(q+1) : r*(q+1) + (xcd-r)*q) + local; }
  const int bm = wg/3, bn = wg - bm*3;
  const int t = threadIdx.x, lane = t&63, wid = t>>6, wr = wid>>1, wc = wid&1;
  const int row0 = bm*64, col0 = bn*128;

  int ob = t*16, r = ob>>6, ke = (ob&63)>>1;
  long aoff = (long)(row0+r)*DD + ke;   // M multiple of 64: no clamp
  int asoff = ob;
  long boff[2]; int bsoff[2];
  #pragma unroll
  for (int i=0;i<2;i++){
    int ob2 = (i*256+t)*16, r2 = ob2>>6, ke2 = (ob2&63)>>1;
    boff[i] = (long)(col0+r2)*DD + ke2; bsoff[i] = ob2;   // col0+r2 <= 383 < DD
  }

  auto stage = [&](int buf, int k0){
    gload16(A + aoff + k0, (char*)As[buf] + asoff);
    #pragma unroll
    for (int i=0;i<2;i++){
      gload16(B1 + boff[i] + k0, (char*)B1s[buf] + bsoff[i]);
      gload16(B2 + boff[i] + k0, (char*)B2s[buf] + bsoff[i]);
    }
  };

  f32x4 acc1[2][4] = {}, acc2[2][4] = {};
  const int kg = (lane>>4)*8, rl = lane&15;

  stage(0, 0);
  stage(1, 32);
  int buf = 0;
  for (int tt=0; tt<12; ++tt){
    if (tt < 11) WAITV(5); else WAITV(0);
    __builtin_amdgcn_sched_barrier(0);
    __builtin_amdgcn_s_barrier();

    bfv8 af[2], b1r[4], b2r[4];
    #pragma unroll
    for (int m=0;m<2;m++) af[m] = *(const bfv8*)&As[buf][(wr*32 + m*16 + rl)*32 + kg];
    #pragma unroll
    for (int n=0;n<4;n++){
      b1r[n] = *(const bfv8*)&B1s[buf][(wc*64 + n*16 + rl)*32 + kg];
      b2r[n] = *(const bfv8*)&B2s[buf][(wc*64 + n*16 + rl)*32 + kg];
    }
    #pragma unroll
    for (int m=0;m<2;m++)
      #pragma unroll
      for (int n=0;n<4;n++){
        acc1[m][n] = __builtin_amdgcn_mfma_f32_16x16x32_bf16(af[m], b1r[n], acc1[m][n], 0,0,0);
        acc2[m][n] = __builtin_amdgcn_mfma_f32_16x16x32_bf16(af[m], b2r[n], acc2[m][n], 0,0,0);
      }

    __builtin_amdgcn_s_barrier();
    __builtin_amdgcn_sched_barrier(0);
    if (tt+2 < 12) stage(buf, (tt+2)*32);
    buf ^= 1;
  }

  const int rbase = row0 + wr*32 + (lane>>4)*4;
  const int cbase = col0 + wc*64 + rl;
  #pragma unroll
  for (int n=0;n<4;n++){
    int c = cbase + n*16;
    #pragma unroll
    for (int m=0;m<2;m++)
      #pragma unroll
      for (int i=0;i<4;i++){
        long idx = (long)(rbase + m*16 + i)*DD + c;
        float v1 = acc1[m][n][i];
        U[idx] = f2bf(sqrtf(v1*v1 + 1e-8f));
        Y[idx] = f2bf(acc2[m][n][i]);
      }
  }
}

extern "C" void kernel_launch(void* const* d_in, const int* in_sizes, int n_in,
                              void* d_out, int out_size, void* d_ws, size_t ws_size,
                              hipStream_t stream){
  const float* x     = (const float*)d_in[0];
  const float* g1    = (const float*)d_in[1];
  const float* b1n   = (const float*)d_in[2];
  const float* V     = (const float*)d_in[3];
  const float* W     = (const float*)d_in[4];
  const float* g2    = (const float*)d_in[5];
  const float* b2n   = (const float*)d_in[6];
  const float* W1    = (const float*)d_in[7];
  const float* bias1 = (const float*)d_in[8];
  const float* W2    = (const float*)d_in[9];
  const float* bias2 = (const float*)d_in[10];
  float* out = (float*)d_out;

  char* ws = (char*)d_ws;
  size_t off = 0;
  auto take = [&](size_t bytes)->char*{ char* p = ws + off; off += (bytes + 255) & ~(size_t)255; return p; };

  float* mu    = (float*)take((size_t)BN*4);
  float* rv    = (float*)take((size_t)BN*4);
  float* scale = (float*)take((size_t)BB*DD*4);
  char* aliasBase = ws + off;                       // G aliases the next 6 (all dead by GEMM5)
  u16*  inpn = (u16*) take((size_t)BN*DD*2);
  u16*  U    = (u16*) take((size_t)BN*DD*2);
  u16*  Ut   = (u16*) take((size_t)BB*DD*NP*2);
  u16*  Yb   = (u16*) take((size_t)BN*DD*2);
  u16*  S    = (u16*) take((size_t)BN*NP*2);
  u16*  attn = (u16*) take((size_t)BN*NP*2);
  u16*  x2   = (u16*) take((size_t)BN*DD*2);
  u16*  h    = (u16*) take((size_t)BN*DD*2);
  u16*  Vb   = (u16*) take((size_t)DD*DD*2);
  u16*  Wt   = (u16*) take((size_t)DD*DD*2);
  u16*  W1t  = (u16*) take((size_t)DD*HH*2);
  u16*  W2t  = (u16*) take((size_t)DD*HH*2);
  u16*  G    = (u16*)aliasBase;                     // 77.5MB <= 102.8MB alias region

  prep_weights<<<DD*HH/256, 256, 0, stream>>>(V, W, W1, W2, Vb, Wt, W1t, W2t);
  ln1_stats  <<<BN/4,       256, 0, stream>>>(x, mu, rv);
  colnorm    <<<BB*DD/256,  256, 0, stream>>>(x, mu, rv, g1, b1n, scale);
  ln_apply   <<<BN*DD/256,  256, 0, stream>>>(x, mu, rv, g1, b1n, scale, inpn);

  // GEMM1+2 fused: U = |inpn.V^T| (natural), Y = inpn.W
  gemm12<<<394*3, 256, 0, stream>>>(inpn, Vb, Wt, U, Yb);
  // transpose + zero-pad: Ut[b][d][224]
  { dim3 grid(BB, DD/32, NP/32);
    transpose_pad<<<grid, 256, 0, stream>>>(U, Ut); }
  // GEMM3 (batched): S = |Y . inpn^T|  (bf16 S)
  { dim3 grid(4*2, BB);
    gemm_nt<64,EpiS><<<grid,256,0,stream>>>(Yb, inpn, NN, NN, DD, DD, DD,
                                         (long)NN*DD, (long)NN*DD, 2, EpiS{S}); }
  softmax_rows<<<BN/4, 256, 0, stream>>>(S, attn);
  // GEMM4 (batched): x2 = bf16(x + attn . Ut^T)   (K=224 zero-padded both sides)
  { dim3 grid(4*3, BB);
    gemm_nt<64,EpiX2><<<grid,256,0,stream>>>(attn, Ut, NN, DD, NP, NP, NP,
                                          (long)NN*NP, (long)DD*NP, 3, EpiX2{x2, x}); }
  ln2_fused<<<BN/4, 256, 0, stream>>>(x2, g2, b2n, h);
  // GEMM5: G = gelu(h . W1 + b1)
  { dim3 grid(197*12, 1);
    gemm_nt<128,EpiGelu><<<grid,256,0,stream>>>(h, W1t, BN, HH, DD, DD, DD, 0, 0, 12, EpiGelu{G, bias1}); }
  // GEMM6: out = x2 + G . W2 + b2
  { dim3 grid(394*3, 1);
    gemm_nt<64,EpiOut><<<grid,256,0,stream>>>(G, W2t, BN, DD, HH, HH, HH, 0, 0, 3, EpiOut{out, x2, bias2}); }
}

// Round 11
// 394.658 us; speedup vs baseline: 1.1031x; 1.0011x over previous
//
#include <hip/hip_runtime.h>
#include <math.h>

typedef unsigned short u16;
typedef unsigned int u32;
typedef __bf16 bfv8 __attribute__((ext_vector_type(8)));
typedef float f32x4 __attribute__((ext_vector_type(4)));
typedef u16 u16v8 __attribute__((ext_vector_type(8)));

#define BB 128
#define NN 197
#define DD 384
#define HH 1536
#define BN (BB*NN)   // 25216 = 197*128, multiple of 128
#define NP 224       // padded attention dim (multiple of 32)

__device__ __forceinline__ float bf2f(u16 h){ u32 u = ((u32)h)<<16; float f; __builtin_memcpy(&f,&u,4); return f; }
__device__ __forceinline__ u16 f2bf(float x){ u32 u; __builtin_memcpy(&u,&x,4); u = (u + 0x7fffu + ((u>>16)&1u))>>16; return (u16)u; }

__device__ __forceinline__ float fast_gelu(float z){
  float t2 = 1.5957691216f*z*(1.f + 0.044715f*z*z);
  return z * __builtin_amdgcn_rcpf(1.f + __expf(-t2));
}

__device__ __forceinline__ void gload16(const void* g, void* s){
  __builtin_amdgcn_global_load_lds(
      (const __attribute__((address_space(1))) void*)g,
      (__attribute__((address_space(3))) void*)s, 16, 0, 0);
}

#define WAITV(N) asm volatile("s_waitcnt vmcnt(" #N ")" ::: "memory")

// ---------------- LN1 row stats ----------------
__global__ __launch_bounds__(256) void ln1_stats(const float* __restrict__ x,
    float* __restrict__ mu, float* __restrict__ rv){
  int row = blockIdx.x*4 + (threadIdx.x>>6);
  int lane = threadIdx.x & 63;
  const float* xr = x + (long)row*DD;
  float s=0.f, ss=0.f;
  #pragma unroll
  for (int j=0;j<DD/64;j++){ float v = xr[lane + j*64]; s+=v; ss+=v*v; }
  #pragma unroll
  for (int m=32;m;m>>=1){ s += __shfl_xor(s,m); ss += __shfl_xor(ss,m); }
  if (lane==0){
    float mn = s*(1.f/DD);
    float var = ss*(1.f/DD) - mn*mn;
    mu[row]=mn; rv[row]=1.f/sqrtf(var+1e-5f);
  }
}

// ---------------- patch-axis norm scale: scale[b,d] ----------------
__global__ __launch_bounds__(256) void colnorm(const float* __restrict__ x,
    const float* __restrict__ mu, const float* __restrict__ rv,
    const float* __restrict__ g, const float* __restrict__ bt,
    float* __restrict__ scale){
  int i = blockIdx.x*256 + threadIdx.x;  // b*DD + d, exact grid
  int b = i/DD, d = i - b*DD;
  const float* xp = x + (long)b*NN*DD + d;
  float gd = g[d], bd = bt[d];
  float s = 0.f;
  for (int n=0;n<NN;n++){
    float v = (xp[(long)n*DD] - mu[b*NN+n]) * rv[b*NN+n] * gd + bd;
    s += v*v;
  }
  scale[i] = 1.f/sqrtf(s + 197.f*1e-4f + 1e-8f);
}

// ---------------- apply LN1 + patch scale -> bf16 ----------------
__global__ __launch_bounds__(256) void ln_apply(const float* __restrict__ x,
    const float* __restrict__ mu, const float* __restrict__ rv,
    const float* __restrict__ g, const float* __restrict__ bt,
    const float* __restrict__ scale, u16* __restrict__ inpn){
  long i = (long)blockIdx.x*256 + threadIdx.x;  // exact grid: BN*DD
  int d = (int)(i % DD);
  long row = i / DD;
  int b = (int)(row / NN);
  float v = (x[i]-mu[row])*rv[row]*g[d]+bt[d];
  inpn[i] = f2bf(v * scale[b*DD+d]);
}

// ---------------- weight prep: plain cast (V) ----------------
__global__ __launch_bounds__(256) void cast_bf16(const float* __restrict__ src, u16* __restrict__ dst, int n){
  int i = blockIdx.x*256 + threadIdx.x;
  if (i < n) dst[i] = f2bf(src[i]);
}

// ---------------- weight prep: transpose + cast via LDS (coalesced both sides) ----------------
// dst[c][r] = bf16(src[r][c]); R,C multiples of 32; grid (R/32, C/32), 256 thr (32x8)
__global__ __launch_bounds__(256) void transpose_cast(const float* __restrict__ src, u16* __restrict__ dst,
    int R, int C){
  __shared__ float tile[32][33];
  int rt = blockIdx.x, ct = blockIdx.y;
  int tx = threadIdx.x & 31, ty = threadIdx.x >> 5;
  #pragma unroll
  for (int j=0;j<4;j++)
    tile[ty+j*8][tx] = src[(long)(rt*32+ty+j*8)*C + ct*32+tx];
  __syncthreads();
  #pragma unroll
  for (int j=0;j<4;j++)
    dst[(long)(ct*32+ty+j*8)*R + rt*32+tx] = f2bf(tile[tx][ty+j*8]);
}

// ---------------- transpose + pad: U[b][n][d] -> Ut[b][d][n(224, zero-pad)] ----------------
__global__ __launch_bounds__(256) void transpose_pad(const u16* __restrict__ U, u16* __restrict__ Ut){
  __shared__ u16 tile[32][33];
  int b = blockIdx.x, dt = blockIdx.y, pt = blockIdx.z;
  int tx = threadIdx.x & 31, ty = threadIdx.x >> 5;   // 32 x 8
  const u16* Ub = U + (long)b*NN*DD;
  #pragma unroll
  for (int j=0;j<4;j++){
    int p = pt*32 + ty + j*8;
    int d = dt*32 + tx;
    tile[ty+j*8][tx] = (p<NN) ? Ub[(long)p*DD + d] : (u16)0;
  }
  __syncthreads();
  u16* Utb = Ut + (long)b*DD*NP;
  #pragma unroll
  for (int j=0;j<4;j++){
    int d = dt*32 + ty + j*8;
    int p = pt*32 + tx;
    Utb[(long)d*NP + p] = tile[tx][ty+j*8];
  }
}

// ---------------- row softmax over 197 (bf16 in), write bf16 padded to 224 ----------------
__global__ __launch_bounds__(256) void softmax_rows(const u16* __restrict__ S, u16* __restrict__ attn){
  int row = blockIdx.x*4 + (threadIdx.x>>6);
  int lane = threadIdx.x & 63;
  const u16* sr = S + (long)row*NP;
  float v[4]; float mx = -1e30f;
  #pragma unroll
  for (int j=0;j<4;j++){ int c = lane + j*64; v[j] = (c<NN)? bf2f(sr[c]) : -1e30f; mx = fmaxf(mx, v[j]); }
  #pragma unroll
  for (int m=32;m;m>>=1) mx = fmaxf(mx, __shfl_xor(mx,m));
  float sm = 0.f;
  #pragma unroll
  for (int j=0;j<4;j++){ v[j] = __expf(v[j]-mx); sm += v[j]; }   // pads -> 0
  #pragma unroll
  for (int m=32;m;m>>=1) sm += __shfl_xor(sm,m);
  float inv = __builtin_amdgcn_rcpf(sm);
  u16* ar = attn + (long)row*NP;
  #pragma unroll
  for (int j=0;j<4;j++){ int c = lane + j*64; if (c<NP) ar[c] = f2bf(v[j]*inv); }
}

// ---------------- LN2 fused (stats + apply), bf16 x2 in -> bf16 h ----------------
__global__ __launch_bounds__(256) void ln2_fused(const u16* __restrict__ x2,
    const float* __restrict__ g, const float* __restrict__ bt, u16* __restrict__ h){
  int row = blockIdx.x*4 + (threadIdx.x>>6);
  int lane = threadIdx.x & 63;
  const u16* xr = x2 + (long)row*DD;
  float v[6]; float s=0.f, ss=0.f;
  #pragma unroll
  for (int j=0;j<6;j++){ v[j]=bf2f(xr[lane+j*64]); s+=v[j]; ss+=v[j]*v[j]; }
  #pragma unroll
  for (int m=32;m;m>>=1){ s+=__shfl_xor(s,m); ss+=__shfl_xor(ss,m); }
  float mn = s*(1.f/DD);
  float rvv = 1.f/sqrtf(ss*(1.f/DD)-mn*mn+1e-5f);
  u16* hr = h + (long)row*DD;
  #pragma unroll
  for (int j=0;j<6;j++){ int d = lane+j*64; hr[d] = f2bf((v[j]-mn)*rvv*g[d]+bt[d]); }
}

// ---------------- epilogue functors (r8 direct-write versions) ----------------
struct EpiS { u16* s;                        // bf16 S
  __device__ void operator()(int b, int r0, int c, const f32x4* col, int mf) const {
    u16* sp = s + ((long)b*NN + r0)*NP + c;
    for (int m=0;m<mf;m++)
      #pragma unroll
      for (int i=0;i<4;i++){
        int r = r0 + m*16 + i;
        float v = col[m][i];
        if (r < NN) sp[(long)(m*16+i)*NP] = f2bf(sqrtf(v*v + 1e-8f));
      }
  }};
struct EpiX2 { u16* x2; const float* x;      // bf16 x2 = x + t
  __device__ void operator()(int b, int r0, int c, const f32x4* col, int mf) const {
    long base = ((long)b*NN + r0)*DD + c;
    for (int m=0;m<mf;m++)
      #pragma unroll
      for (int i=0;i<4;i++){
        int r = r0 + m*16 + i;
        if (r < NN){ long idx = base + (long)(m*16+i)*DD; x2[idx] = f2bf(x[idx] + col[m][i]); }
      }
  }};
struct EpiOut { float* o; const u16* x2; const float* b2;   // fp32 out: direct (sector-aligned)
  __device__ void operator()(int, int r0, int c, const f32x4* col, int mf) const {
    float bb = b2[c];
    long base = (long)r0*DD + c;
    for (int m=0;m<mf;m++)
      #pragma unroll
      for (int i=0;i<4;i++){
        long idx = base + (long)(m*16+i)*DD;
        o[idx] = bf2f(x2[idx]) + col[m][i] + bb;
      }
  }};

// ---------------- generic NT GEMM (r8-verbatim): C = A(MxK) * B(NxK)^T ----------------
// BM x 128 tile, BK=32, 4 waves (2x2), 2-buffer counted-vmcnt pipeline (T4):
//   wait vmcnt(L) -> s_barrier -> ds_read+MFMA -> s_barrier -> restage freed buf
// XCD-aware bijective blockIdx swizzle (T1/m204) for A-panel L2 sharing.
template<int BM, class Epi>
__global__ __launch_bounds__(256) void gemm_nt(const u16* __restrict__ A, const u16* __restrict__ B,
    int M, int N, int K, int lda, int ldb, long sA, long sB, int NT, Epi epi)
{
  constexpr int MF = BM/32;          // row fragments per wave
  constexpr int ALOADS = BM/64;      // gload16 per thread for A tile
  __shared__ __align__(16) u16 As[2][BM*32];
  __shared__ __align__(16) u16 Bs[2][128*32];
  int wg;
  { int flat = blockIdx.x, nwg = gridDim.x;
    int xcd = flat & 7, local = flat >> 3;
    int q = nwg >> 3, r = nwg & 7;
    wg = (xcd < r ? xcd*(q+1) : r*(q+1) + (xcd-r)*q) + local; }
  const int bm = wg / NT, bn = wg - bm*NT;
  const int bat = blockIdx.y;
  const u16* Ab = A + (long)bat*sA;
  const u16* Bb = B + (long)bat*sB;
  const int t = threadIdx.x, lane = t&63, wid = t>>6, wr = wid>>1, wc = wid&1;
  const int row0 = bm*BM, col0 = bn*128;

  long aoff[ALOADS]; int asoff[ALOADS];
  #pragma unroll
  for (int i=0;i<ALOADS;i++){
    int ob = (i*256+t)*16;
    int r = ob>>6, ke = (ob&63)>>1;
    int ra = row0+r; if (ra>M-1) ra=M-1;   // clamp edge rows (valid mem, outputs guarded)
    aoff[i] = (long)ra*lda + ke; asoff[i] = ob;
  }
  long boff[2]; int bsoff[2];
  #pragma unroll
  for (int i=0;i<2;i++){
    int ob = (i*256+t)*16;
    int r = ob>>6, ke = (ob&63)>>1;
    int rb = col0+r; if (rb>N-1) rb=N-1;
    boff[i] = (long)rb*ldb + ke; bsoff[i] = ob;
  }

  auto stage = [&](int buf, int k0){
    #pragma unroll
    for (int i=0;i<ALOADS;i++) gload16(Ab + aoff[i] + k0, (char*)As[buf] + asoff[i]);
    #pragma unroll
    for (int i=0;i<2;i++)      gload16(Bb + boff[i] + k0, (char*)Bs[buf] + bsoff[i]);
  };

  f32x4 acc[MF][4] = {};
  const int kg = (lane>>4)*8, rl = lane&15;
  const int ntile = K/32;

  stage(0, 0);
  stage(1, 32);
  int buf = 0;
  for (int tt=0; tt<ntile; ++tt){
    if (tt+1 < ntile){
      if constexpr (ALOADS == 1) WAITV(3); else WAITV(4);
    } else {
      WAITV(0);
    }
    __builtin_amdgcn_sched_barrier(0);
    __builtin_amdgcn_s_barrier();      // all waves' portions of tile tt landed

    bfv8 af[MF], bfr[4];
    #pragma unroll
    for (int m=0;m<MF;m++) af[m]  = *(const bfv8*)&As[buf][(wr*(BM/2) + m*16 + rl)*32 + kg];
    #pragma unroll
    for (int n=0;n<4;n++)  bfr[n] = *(const bfv8*)&Bs[buf][(wc*64 + n*16 + rl)*32 + kg];
    #pragma unroll
    for (int m=0;m<MF;m++)
      #pragma unroll
      for (int n=0;n<4;n++)
        acc[m][n] = __builtin_amdgcn_mfma_f32_16x16x32_bf16(af[m], bfr[n], acc[m][n], 0,0,0);

    __builtin_amdgcn_s_barrier();      // all waves consumed buf
    __builtin_amdgcn_sched_barrier(0);
    if (tt+2 < ntile) stage(buf, (tt+2)*32);
    buf ^= 1;
  }

  const int rbase = row0 + wr*(BM/2) + (lane>>4)*4;
  const int cbase = col0 + wc*64 + rl;
  #pragma unroll
  for (int n=0;n<4;n++){
    int c = cbase + n*16;
    if (c < N){
      f32x4 colv[MF];
      #pragma unroll
      for (int m=0;m<MF;m++) colv[m] = acc[m][n];
      epi(bat, rbase, c, colv, MF);
    }
  }
}

// ---------------- GEMM5 with dedicated coalesced output tile ----------------
// G = gelu(h . W1t^T + b1). M=BN, N=HH, K=DD, NT=12, BM=128. Same K-loop as
// gemm_nt<128>; epilogue stages bf16 output in a SEPARATE otile (no aliasing
// with As/Bs -> no interaction with the staging pipeline; textbook
// write -> __syncthreads -> coalesced read, same pattern as transpose_pad).
// Fixes r8's measured 1.55x write amplification (120MB for 77.5MB logical).
__global__ __launch_bounds__(256) void gemm5_coal(const u16* __restrict__ A, const u16* __restrict__ B,
    const float* __restrict__ b1, u16* __restrict__ G)
{
  __shared__ __align__(16) u16 As[2][128*32];
  __shared__ __align__(16) u16 Bs[2][128*32];
  __shared__ __align__(16) u16 otile[128*128];
  int wg;
  { int flat = blockIdx.x, nwg = gridDim.x;
    int xcd = flat & 7, local = flat >> 3;
    int q = nwg >> 3, r = nwg & 7;
    wg = (xcd < r ? xcd*(q+1) : r*(q+1) + (xcd-r)*q) + local; }
  const int bm = wg / 12, bn = wg - bm*12;
  const int t = threadIdx.x, lane = t&63, wid = t>>6, wr = wid>>1, wc = wid&1;
  const int row0 = bm*128, col0 = bn*128;

  long aoff[2], boff[2]; int soff[2];
  #pragma unroll
  for (int i=0;i<2;i++){
    int ob = (i*256+t)*16;
    int r = ob>>6, ke = (ob&63)>>1;
    aoff[i] = (long)(row0+r)*DD + ke;    // M=BN mult of 128, N=HH mult of 128: no clamps
    boff[i] = (long)(col0+r)*DD + ke;
    soff[i] = ob;
  }

  auto stage = [&](int buf, int k0){
    #pragma unroll
    for (int i=0;i<2;i++){
      gload16(A + aoff[i] + k0, (char*)As[buf] + soff[i]);
      gload16(B + boff[i] + k0, (char*)Bs[buf] + soff[i]);
    }
  };

  f32x4 acc[4][4] = {};
  const int kg = (lane>>4)*8, rl = lane&15;

  stage(0, 0);
  stage(1, 32);
  int buf = 0;
  for (int tt=0; tt<12; ++tt){
    if (tt < 11) WAITV(4); else WAITV(0);
    __builtin_amdgcn_sched_barrier(0);
    __builtin_amdgcn_s_barrier();

    bfv8 af[4], bfr[4];
    #pragma unroll
    for (int m=0;m<4;m++) af[m]  = *(const bfv8*)&As[buf][(wr*64 + m*16 + rl)*32 + kg];
    #pragma unroll
    for (int n=0;n<4;n++) bfr[n] = *(const bfv8*)&Bs[buf][(wc*64 + n*16 + rl)*32 + kg];
    #pragma unroll
    for (int m=0;m<4;m++)
      #pragma unroll
      for (int n=0;n<4;n++)
        acc[m][n] = __builtin_amdgcn_mfma_f32_16x16x32_bf16(af[m], bfr[n], acc[m][n], 0,0,0);

    __builtin_amdgcn_s_barrier();
    __builtin_amdgcn_sched_barrier(0);
    if (tt+2 < 12) stage(buf, (tt+2)*32);
    buf ^= 1;
  }

  // epilogue: gelu -> otile (disjoint LDS) -> sync -> coalesced 16B stores
  const int rloc = wr*64 + (lane>>4)*4;
  #pragma unroll
  for (int n=0;n<4;n++){
    int cl = wc*64 + n*16 + rl;
    float bb = b1[col0 + cl];
    #pragma unroll
    for (int m=0;m<4;m++)
      #pragma unroll
      for (int i=0;i<4;i++)
        otile[(rloc + m*16 + i)*128 + cl] = f2bf(fast_gelu(acc[m][n][i] + bb));
  }
  __syncthreads();
  #pragma unroll
  for (int k=0;k<8;k++){
    int chunk = k*256 + t;
    int row = chunk>>4, col8 = (chunk&15)*8;
    *(u16v8*)(G + (long)(row0+row)*HH + col0 + col8) = *(const u16v8*)&otile[row*128 + col8];
  }
}

// ---------------- fused GEMM1+GEMM2 (r8-verbatim): one A-stage, two Bs ----------------
__global__ __launch_bounds__(256) void gemm12(const u16* __restrict__ A,
    const u16* __restrict__ B1, const u16* __restrict__ B2,
    u16* __restrict__ U, u16* __restrict__ Y)
{
  __shared__ __align__(16) u16 As[2][64*32];
  __shared__ __align__(16) u16 B1s[2][128*32];
  __shared__ __align__(16) u16 B2s[2][128*32];
  int wg;
  { int flat = blockIdx.x, nwg = gridDim.x;
    int xcd = flat & 7, local = flat >> 3;
    int q = nwg >> 3, r = nwg & 7;
    wg = (xcd < r ? xcd*(q+1) : r*(q+1) + (xcd-r)*q) + local; }
  const int bm = wg/3, bn = wg - bm*3;
  const int t = threadIdx.x, lane = t&63, wid = t>>6, wr = wid>>1, wc = wid&1;
  const int row0 = bm*64, col0 = bn*128;

  int ob = t*16, r = ob>>6, ke = (ob&63)>>1;
  long aoff = (long)(row0+r)*DD + ke;   // M multiple of 64: no clamp
  int asoff = ob;
  long boff[2]; int bsoff[2];
  #pragma unroll
  for (int i=0;i<2;i++){
    int ob2 = (i*256+t)*16, r2 = ob2>>6, ke2 = (ob2&63)>>1;
    boff[i] = (long)(col0+r2)*DD + ke2; bsoff[i] = ob2;
  }

  auto stage = [&](int buf, int k0){
    gload16(A + aoff + k0, (char*)As[buf] + asoff);
    #pragma unroll
    for (int i=0;i<2;i++){
      gload16(B1 + boff[i] + k0, (char*)B1s[buf] + bsoff[i]);
      gload16(B2 + boff[i] + k0, (char*)B2s[buf] + bsoff[i]);
    }
  };

  f32x4 acc1[2][4] = {}, acc2[2][4] = {};
  const int kg = (lane>>4)*8, rl = lane&15;

  stage(0, 0);
  stage(1, 32);
  int buf = 0;
  for (int tt=0; tt<12; ++tt){
    if (tt < 11) WAITV(5); else WAITV(0);
    __builtin_amdgcn_sched_barrier(0);
    __builtin_amdgcn_s_barrier();

    bfv8 af[2], b1r[4], b2r[4];
    #pragma unroll
    for (int m=0;m<2;m++) af[m] = *(const bfv8*)&As[buf][(wr*32 + m*16 + rl)*32 + kg];
    #pragma unroll
    for (int n=0;n<4;n++){
      b1r[n] = *(const bfv8*)&B1s[buf][(wc*64 + n*16 + rl)*32 + kg];
      b2r[n] = *(const bfv8*)&B2s[buf][(wc*64 + n*16 + rl)*32 + kg];
    }
    #pragma unroll
    for (int m=0;m<2;m++)
      #pragma unroll
      for (int n=0;n<4;n++){
        acc1[m][n] = __builtin_amdgcn_mfma_f32_16x16x32_bf16(af[m], b1r[n], acc1[m][n], 0,0,0);
        acc2[m][n] = __builtin_amdgcn_mfma_f32_16x16x32_bf16(af[m], b2r[n], acc2[m][n], 0,0,0);
      }

    __builtin_amdgcn_s_barrier();
    __builtin_amdgcn_sched_barrier(0);
    if (tt+2 < 12) stage(buf, (tt+2)*32);
    buf ^= 1;
  }

  const int rbase = row0 + wr*32 + (lane>>4)*4;
  const int cbase = col0 + wc*64 + rl;
  #pragma unroll
  for (int n=0;n<4;n++){
    int c = cbase + n*16;
    #pragma unroll
    for (int m=0;m<2;m++)
      #pragma unroll
      for (int i=0;i<4;i++){
        long idx = (long)(rbase + m*16 + i)*DD + c;
        float v1 = acc1[m][n][i];
        U[idx] = f2bf(sqrtf(v1*v1 + 1e-8f));
        Y[idx] = f2bf(acc2[m][n][i]);
      }
  }
}

extern "C" void kernel_launch(void* const* d_in, const int* in_sizes, int n_in,
                              void* d_out, int out_size, void* d_ws, size_t ws_size,
                              hipStream_t stream){
  const float* x     = (const float*)d_in[0];
  const float* g1    = (const float*)d_in[1];
  const float* b1n   = (const float*)d_in[2];
  const float* V     = (const float*)d_in[3];
  const float* W     = (const float*)d_in[4];
  const float* g2    = (const float*)d_in[5];
  const float* b2n   = (const float*)d_in[6];
  const float* W1    = (const float*)d_in[7];
  const float* bias1 = (const float*)d_in[8];
  const float* W2    = (const float*)d_in[9];
  const float* bias2 = (const float*)d_in[10];
  float* out = (float*)d_out;

  char* ws = (char*)d_ws;
  size_t off = 0;
  auto take = [&](size_t bytes)->char*{ char* p = ws + off; off += (bytes + 255) & ~(size_t)255; return p; };

  float* mu    = (float*)take((size_t)BN*4);
  float* rv    = (float*)take((size_t)BN*4);
  float* scale = (float*)take((size_t)BB*DD*4);
  char* aliasBase = ws + off;                       // G aliases inpn..attn (dead by GEMM5)
  u16*  inpn = (u16*) take((size_t)BN*DD*2);
  u16*  U    = (u16*) take((size_t)BN*DD*2);
  u16*  Ut   = (u16*) take((size_t)BB*DD*NP*2);
  u16*  Yb   = (u16*) take((size_t)BN*DD*2);
  u16*  S    = (u16*) take((size_t)BN*NP*2);
  u16*  attn = (u16*) take((size_t)BN*NP*2);
  u16*  x2   = (u16*) take((size_t)BN*DD*2);      // starts at ~102.7MB > G's 77.5MB: safe
  u16*  h    = (u16*) take((size_t)BN*DD*2);
  u16*  Vb   = (u16*) take((size_t)DD*DD*2);
  u16*  Wt   = (u16*) take((size_t)DD*DD*2);
  u16*  W1t  = (u16*) take((size_t)DD*HH*2);
  u16*  W2t  = (u16*) take((size_t)DD*HH*2);
  u16*  G    = (u16*)aliasBase;                     // 77.5MB < inpn..attn region

  cast_bf16<<<DD*DD/256, 256, 0, stream>>>(V, Vb, DD*DD);
  { dim3 g(DD/32, DD/32); transpose_cast<<<g, 256, 0, stream>>>(W,  Wt,  DD, DD); }
  { dim3 g(DD/32, HH/32); transpose_cast<<<g, 256, 0, stream>>>(W1, W1t, DD, HH); }
  { dim3 g(HH/32, DD/32); transpose_cast<<<g, 256, 0, stream>>>(W2, W2t, HH, DD); }
  ln1_stats  <<<BN/4,       256, 0, stream>>>(x, mu, rv);
  colnorm    <<<BB*DD/256,  256, 0, stream>>>(x, mu, rv, g1, b1n, scale);
  ln_apply   <<<BN*DD/256,  256, 0, stream>>>(x, mu, rv, g1, b1n, scale, inpn);

  // GEMM1+2 fused: U = |inpn.V^T| (natural), Y = inpn.W
  gemm12<<<394*3, 256, 0, stream>>>(inpn, Vb, Wt, U, Yb);
  // transpose + zero-pad: Ut[b][d][224]
  { dim3 grid(BB, DD/32, NP/32);
    transpose_pad<<<grid, 256, 0, stream>>>(U, Ut); }
  // GEMM3 (batched): S = |Y . inpn^T|  (bf16 S)
  { dim3 grid(4*2, BB);
    gemm_nt<64,EpiS><<<grid,256,0,stream>>>(Yb, inpn, NN, NN, DD, DD, DD,
                                         (long)NN*DD, (long)NN*DD, 2, EpiS{S}); }
  softmax_rows<<<BN/4, 256, 0, stream>>>(S, attn);
  // GEMM4 (batched): x2 = bf16(x + attn . Ut^T)   (K=224 zero-padded both sides)
  { dim3 grid(4*3, BB);
    gemm_nt<64,EpiX2><<<grid,256,0,stream>>>(attn, Ut, NN, DD, NP, NP, NP,
                                          (long)NN*NP, (long)DD*NP, 3, EpiX2{x2, x}); }
  ln2_fused<<<BN/4, 256, 0, stream>>>(x2, g2, b2n, h);
  // GEMM5: G = gelu(h . W1 + b1)  -- coalesced-output variant
  gemm5_coal<<<197*12, 256, 0, stream>>>(h, W1t, bias1, G);
  // GEMM6: out = x2 + G . W2 + b2
  { dim3 grid(394*3, 1);
    gemm_nt<64,EpiOut><<<grid,256,0,stream>>>(G, W2t, BN, DD, HH, HH, HH, 0, 0, 3,
                                          EpiOut{out, x2, bias2}); }
}